// Round 5
// baseline (322.209 us; speedup 1.0000x reference)
//
#include <hip/hip_runtime.h>

typedef unsigned short u16;
typedef unsigned int u32;
typedef __attribute__((ext_vector_type(4))) float f32x4;
typedef __attribute__((ext_vector_type(8))) __bf16 bf16x8;
typedef __attribute__((ext_vector_type(4))) u16 u16x4;

__device__ __forceinline__ u16 f2bf(float f) {
  u32 u = __float_as_uint(f);
  u32 r = (u + 0x7fffu + ((u >> 16) & 1u)) >> 16;
  return (u16)r;
}

__device__ __forceinline__ float load_thr(const int* p) {
  int iv = *p;
  float fv = __int_as_float(iv);
  if (fv >= 1.0f && fv <= 1.0e6f) return fv;
  return (float)iv;
}

__device__ __forceinline__ void gload_lds16(const void* g, void* l) {
  __builtin_amdgcn_global_load_lds(
      (const __attribute__((address_space(1))) void*)g,
      (__attribute__((address_space(3))) void*)l, 16, 0, 0);
}

// ---------------- colmax over rows of x ----------------
__global__ void k_init_cm(u32* cm, int K) {
  int i = blockIdx.x * 256 + threadIdx.x;
  if (i < K) cm[i] = 0u;
}

__global__ __launch_bounds__(256) void k_colmax(const float* __restrict__ x,
                                                u32* __restrict__ cm, int M,
                                                int K, int rpb) {
  int c4 = blockIdx.x * 256 + threadIdx.x;
  int r0 = blockIdx.y * rpb;
  int r1 = r0 + rpb;
  if (r1 > M) r1 = M;
  f32x4 mx = {0.f, 0.f, 0.f, 0.f};
  for (int r = r0; r < r1; ++r) {
    f32x4 v = *(const f32x4*)&x[(size_t)r * K + (size_t)c4 * 4];
#pragma unroll
    for (int i = 0; i < 4; ++i) mx[i] = fmaxf(mx[i], fabsf(v[i]));
  }
#pragma unroll
  for (int i = 0; i < 4; ++i)
    atomicMax(&cm[c4 * 4 + i], __float_as_uint(mx[i]));
}

// ---------------- row-wise quant-dequant -> bf16 operand ----------------
__global__ __launch_bounds__(256) void k_quant(
    const float* __restrict__ src, const u32* __restrict__ cm,
    const int* __restrict__ thr_i, u16* __restrict__ dst, int K,
    int exclude_outlier_from_max) {
  int row = blockIdx.x;
  int tid = threadIdx.x;
  float thr = load_thr(thr_i);
  const float* sr = src + (size_t)row * K;
  const float* cmf = (const float*)cm;

  float v[16];
  u32 omask = 0;
  float lmax = 0.f;
#pragma unroll
  for (int j = 0; j < 4; ++j) {
    int c4 = j * 256 + tid;
    f32x4 val = *(const f32x4*)&sr[c4 * 4];
    f32x4 cv = *(const f32x4*)&cmf[c4 * 4];
#pragma unroll
    for (int i = 0; i < 4; ++i) {
      float xv = val[i];
      v[j * 4 + i] = xv;
      bool is_out = cv[i] > thr;
      if (is_out) omask |= 1u << (j * 4 + i);
      if (!is_out || !exclude_outlier_from_max) lmax = fmaxf(lmax, fabsf(xv));
    }
  }
  float m = lmax;
#pragma unroll
  for (int off = 32; off >= 1; off >>= 1) m = fmaxf(m, __shfl_down(m, off));
  __shared__ float red[4];
  int lane = tid & 63, wv = tid >> 6;
  if (lane == 0) red[wv] = m;
  __syncthreads();
  float rm = fmaxf(fmaxf(red[0], red[1]), fmaxf(red[2], red[3]));
  float s = fmaxf(rm / 127.0f, 1e-8f);

#pragma unroll
  for (int j = 0; j < 4; ++j) {
    int c4 = j * 256 + tid;
    u16x4 ov;
#pragma unroll
    for (int i = 0; i < 4; ++i) {
      float xv = v[j * 4 + i];
      float dq;
      if (omask & (1u << (j * 4 + i))) {
        dq = xv;
      } else {
        float q = rintf(xv / s);
        q = fminf(fmaxf(q, -127.f), 127.f);
        dq = q * s;
      }
      ov[i] = f2bf(dq);
    }
    *(u16x4*)&dst[(size_t)row * K + c4 * 4] = ov;
  }
}

// ---------------- 256x256 8-phase bf16 GEMM (NT): out = A @ B^T + bias ----
// m201 template + A-fragment register double-buffering: each phase's A
// ds_reads are issued one phase early (during the previous MFMA cluster),
// and the pre-MFMA wait is a counted lgkmcnt(4) instead of a full drain.
#define BM 256
#define BN 256

__global__ __launch_bounds__(512, 2) void k_gemm8(
    const u16* __restrict__ Aq, const u16* __restrict__ Bq,
    const float* __restrict__ bias, float* __restrict__ out, int M, int N,
    int K) {
  extern __shared__ u16 lds_raw[];
  // [buf][op A=0/B=1][half][128*64 u16] ; total 128 KiB
  u16(*lds)[2][2][128 * 64] = (u16(*)[2][2][128 * 64])lds_raw;

  int tid = threadIdx.x;
  int lane = tid & 63, wave = tid >> 6;
  int wm = wave >> 2, wn = wave & 3;  // 2 x 4 wave grid

  // T1: bijective XCD swizzle (nwg % 8 == 0)
  int nwg = gridDim.x;
  int bid = blockIdx.x;
  int swz = (bid & 7) * (nwg >> 3) + (bid >> 3);
  int nbn = N / BN;
  int bm = swz / nbn, bn = swz % nbn;
  int r0 = bm * BM, c0 = bn * BN;

  // staging: per thread 2x global_load_lds(16B) per half-tile (128x64 u16).
  // LDS dest linear (granule g); global source pre-swizzled so LDS granule
  // (row, gc) holds linear granule (row, gc ^ (row&7)) — involution.
  int g0 = tid, g1 = 512 + tid;
  int row0s = g0 >> 3, col0e = ((g0 & 7) ^ ((g0 >> 3) & 7)) << 3;
  int row1s = g1 >> 3, col1e = ((g1 & 7) ^ ((g1 >> 3) & 7)) << 3;

#define STAGE(dstp, srcb, rowbase, kb)                                        \
  {                                                                           \
    gload_lds16(&(srcb)[(size_t)((rowbase) + row0s) * K + (kb) + col0e],      \
                &(dstp)[(size_t)g0 * 8]);                                     \
    gload_lds16(&(srcb)[(size_t)((rowbase) + row1s) * K + (kb) + col1e],      \
                &(dstp)[(size_t)g1 * 8]);                                     \
  }

  // ds_read of one 16x16x32 fragment (8 bf16 = 16B), slot ^= row&7 swizzle
#define LDA(dst, buf, i, ks)                                                  \
  {                                                                           \
    int rl = (i) * 16 + (lane & 15);                                          \
    int off = rl * 128 + ((((ks) * 4 + (lane >> 4)) ^ (rl & 7)) << 4);        \
    dst = *(const bf16x8*)((const char*)lds[buf][0][wm] + off);               \
  }
#define LDB(dst, buf, j, ks)                                                  \
  {                                                                           \
    int rl = ((wn & 1) << 6) + (j) * 16 + (lane & 15);                        \
    int off = rl * 128 + ((((ks) * 4 + (lane >> 4)) ^ (rl & 7)) << 4);        \
    dst = *(const bf16x8*)((const char*)lds[buf][1][wn >> 1] + off);          \
  }

#define MF(i, j, av, bv) \
  acc[i][j] = __builtin_amdgcn_mfma_f32_16x16x32_bf16(av, bv, acc[i][j], 0, 0, 0)

  // 16-MFMA cluster for acc row-pair (rb, rb+1) from A-frag set S[4]
#define CL16(rb, S)                                                           \
  {                                                                           \
    __builtin_amdgcn_s_setprio(1);                                            \
    MF(rb, 0, S[0], Bf[0]);                                                   \
    MF(rb, 1, S[0], Bf[1]);                                                   \
    MF(rb, 2, S[0], Bf[2]);                                                   \
    MF(rb, 3, S[0], Bf[3]);                                                   \
    MF((rb) + 1, 0, S[2], Bf[0]);                                             \
    MF((rb) + 1, 1, S[2], Bf[1]);                                             \
    MF((rb) + 1, 2, S[2], Bf[2]);                                             \
    MF((rb) + 1, 3, S[2], Bf[3]);                                             \
    MF(rb, 0, S[1], Bf[4]);                                                   \
    MF(rb, 1, S[1], Bf[5]);                                                   \
    MF(rb, 2, S[1], Bf[6]);                                                   \
    MF(rb, 3, S[1], Bf[7]);                                                   \
    MF((rb) + 1, 0, S[3], Bf[4]);                                             \
    MF((rb) + 1, 1, S[3], Bf[5]);                                             \
    MF((rb) + 1, 2, S[3], Bf[6]);                                             \
    MF((rb) + 1, 3, S[3], Bf[7]);                                             \
    __builtin_amdgcn_s_setprio(0);                                            \
  }

#define LDA4(S, ib, buf)                                                      \
  {                                                                           \
    LDA(S[0], buf, ib, 0);                                                    \
    LDA(S[1], buf, ib, 1);                                                    \
    LDA(S[2], buf, (ib) + 1, 0);                                              \
    LDA(S[3], buf, (ib) + 1, 1);                                              \
  }

#define BAR __builtin_amdgcn_s_barrier()
#define WL4 asm volatile("s_waitcnt lgkmcnt(4)" ::: "memory")
#define WL0 asm volatile("s_waitcnt lgkmcnt(0)" ::: "memory")
#define WV4 asm volatile("s_waitcnt vmcnt(4)" ::: "memory")

  // 4-phase group over one staged K-tile (buf): A-frag reads pipelined one
  // phase ahead in afr0/afr1 (all indices compile-time — rule #20).
#define GROUP(buf, P1, P2, P3, P4)                                            \
  {                                                                           \
    /* q0: B all 8, A for q0 (afr0) and q1 (afr1) */                          \
    LDB(Bf[0], buf, 0, 0); LDB(Bf[1], buf, 1, 0);                             \
    LDB(Bf[2], buf, 2, 0); LDB(Bf[3], buf, 3, 0);                             \
    LDB(Bf[4], buf, 0, 1); LDB(Bf[5], buf, 1, 1);                             \
    LDB(Bf[6], buf, 2, 1); LDB(Bf[7], buf, 3, 1);                             \
    LDA4(afr0, 0, buf);                                                       \
    LDA4(afr1, 2, buf);                                                       \
    P1; BAR; WL4; CL16(0, afr0); BAR;                                         \
    /* q1: prefetch q2's A into afr0; compute q1 from afr1 */                 \
    LDA4(afr0, 4, buf);                                                       \
    P2; BAR; WL4; CL16(2, afr1); BAR;                                         \
    /* q2: prefetch q3's A into afr1; compute q2 from afr0 */                 \
    LDA4(afr1, 6, buf);                                                       \
    P3; BAR; WL4; CL16(4, afr0); BAR;                                         \
    /* q3: no prefetch (next buf is vmcnt-guarded); compute from afr1 */      \
    P4; BAR; WL0; CL16(6, afr1); WV4; BAR;                                    \
  }

  f32x4 acc[8][4] = {};
  bf16x8 Bf[8];
  bf16x8 afr0[4], afr1[4];

  // prologue: tile0 full into buf0, tile1 B-halves into buf1
  STAGE(lds[0][0][0], Aq, r0, 0);
  STAGE(lds[0][0][1], Aq, r0 + 128, 0);
  STAGE(lds[0][1][0], Bq, c0, 0);
  STAGE(lds[0][1][1], Bq, c0 + 128, 0);
  STAGE(lds[1][1][0], Bq, c0, 64);
  STAGE(lds[1][1][1], Bq, c0 + 128, 64);
  WV4;
  BAR;

  int nit = K / 128;  // 2 K-tiles per iteration
  for (int it = 0; it < nit; ++it) {
    int kt1 = it * 128 + 64;  // tile t+1 (always < K)
    int kb2 = it * 128 + 128;
    kb2 = (kb2 < K) ? kb2 : 0;  // tile t+2 (clamped; unused if OOB)
    int kb3 = it * 128 + 192;
    kb3 = (kb3 < K) ? kb3 : 0;  // tile t+3 (clamped)
    // phases 1-4: compute tile t from buf0
    GROUP(0, STAGE(lds[1][0][0], Aq, r0, kt1),
          STAGE(lds[1][0][1], Aq, r0 + 128, kt1),
          STAGE(lds[0][1][0], Bq, c0, kb2),
          STAGE(lds[0][1][1], Bq, c0 + 128, kb2));
    // phases 5-8: compute tile t+1 from buf1
    GROUP(1, STAGE(lds[0][0][0], Aq, r0, kb2),
          STAGE(lds[0][0][1], Aq, r0 + 128, kb2),
          STAGE(lds[1][1][0], Bq, c0, kb3),
          STAGE(lds[1][1][1], Bq, c0 + 128, kb3));
  }

  // epilogue: C/D layout col=lane&15, row=(lane>>4)*4+reg
  int lr = (lane >> 4) << 2, lc = lane & 15;
  float bv[4];
#pragma unroll
  for (int j = 0; j < 4; ++j) bv[j] = bias[c0 + wn * 64 + j * 16 + lc];
#pragma unroll
  for (int i = 0; i < 8; ++i) {
#pragma unroll
    for (int r = 0; r < 4; ++r) {
      int gm = r0 + wm * 128 + i * 16 + lr + r;
      float* orow = out + (size_t)gm * N + c0 + wn * 64 + lc;
#pragma unroll
      for (int j = 0; j < 4; ++j) orow[j * 16] = acc[i][j][r] + bv[j];
    }
  }
}

extern "C" void kernel_launch(void* const* d_in, const int* in_sizes, int n_in,
                              void* d_out, int out_size, void* d_ws,
                              size_t ws_size, hipStream_t stream) {
  const float* x = (const float*)d_in[0];
  const float* W = (const float*)d_in[1];
  const float* bias = (const float*)d_in[2];
  const int* thr = (const int*)d_in[3];
  float* out = (float*)d_out;

  int N = in_sizes[2];
  int K = in_sizes[1] / N;
  int M = in_sizes[0] / K;

  u32* cm = (u32*)d_ws;
  u16* Aq = (u16*)((char*)d_ws + 16384);
  u16* Bq = (u16*)((char*)d_ws + 16384 + (size_t)M * K * sizeof(u16));

  k_init_cm<<<dim3((K + 255) / 256), dim3(256), 0, stream>>>(cm, K);

  {
    int gx = K / 1024;
    int gy = 128;
    int rpb = (M + gy - 1) / gy;
    k_colmax<<<dim3(gx, gy), dim3(256), 0, stream>>>(x, cm, M, K, rpb);
  }

  k_quant<<<dim3(M), dim3(256), 0, stream>>>(x, cm, thr, Aq, K, 1);
  k_quant<<<dim3(N), dim3(256), 0, stream>>>(W, cm, thr, Bq, K, 0);

  (void)hipFuncSetAttribute((const void*)k_gemm8,
                            hipFuncAttributeMaxDynamicSharedMemorySize,
                            131072);
  int nwg = (M / BM) * (N / BN);
  k_gemm8<<<dim3(nwg), dim3(512), 131072, stream>>>(Aq, Bq, bias, out, M, N,
                                                    K);
}

// Round 6
// 253.058 us; speedup vs baseline: 1.2733x; 1.2733x over previous
//
#include <hip/hip_runtime.h>

typedef unsigned short u16;
typedef unsigned char u8;
typedef unsigned int u32;
typedef __attribute__((ext_vector_type(4))) float f32x4;
typedef __attribute__((ext_vector_type(16))) float f32x16;
typedef __attribute__((ext_vector_type(8))) __bf16 bf16x8;
typedef __attribute__((ext_vector_type(4))) int i32x4;
typedef __attribute__((ext_vector_type(16))) int i32x16;

__device__ __forceinline__ u16 f2bf(float f) {
  u32 u = __float_as_uint(f);
  u32 r = (u + 0x7fffu + ((u >> 16) & 1u)) >> 16;
  return (u16)r;
}

__device__ __forceinline__ float load_thr(const int* p) {
  int iv = *p;
  float fv = __int_as_float(iv);
  if (fv >= 1.0f && fv <= 1.0e6f) return fv;
  return (float)iv;
}

__device__ __forceinline__ void gload_lds16(const void* g, void* l) {
  __builtin_amdgcn_global_load_lds(
      (const __attribute__((address_space(1))) void*)g,
      (__attribute__((address_space(3))) void*)l, 16, 0, 0);
}

// ---------------- colmax over rows of x ----------------
__global__ void k_init_cm(u32* cm, int K) {
  int i = blockIdx.x * 256 + threadIdx.x;
  if (i < K) cm[i] = 0u;
}

__global__ __launch_bounds__(256) void k_colmax(const float* __restrict__ x,
                                                u32* __restrict__ cm, int M,
                                                int K, int rpb) {
  int c4 = blockIdx.x * 256 + threadIdx.x;
  int r0 = blockIdx.y * rpb;
  int r1 = r0 + rpb;
  if (r1 > M) r1 = M;
  f32x4 mx = {0.f, 0.f, 0.f, 0.f};
  for (int r = r0; r < r1; ++r) {
    f32x4 v = *(const f32x4*)&x[(size_t)r * K + (size_t)c4 * 4];
#pragma unroll
    for (int i = 0; i < 4; ++i) mx[i] = fmaxf(mx[i], fabsf(v[i]));
  }
#pragma unroll
  for (int i = 0; i < 4; ++i)
    atomicMax(&cm[c4 * 4 + i], __float_as_uint(mx[i]));
}

// ---------------- ordered outlier-column compaction (1 wave) -------------
// meta[0] = n_out (capped 64); meta[1..64] = ordered col indices, -1 pad.
__global__ void k_ocols(const u32* __restrict__ cm, const int* __restrict__ thr_i,
                        int K, int* __restrict__ meta) {
  int lane = threadIdx.x;  // 64 threads
  float thr = load_thr(thr_i);
  const float* cmf = (const float*)cm;
  int per = K >> 6;
  int base = lane * per;
  int c = 0;
  for (int i = 0; i < per; ++i) c += (cmf[base + i] > thr) ? 1 : 0;
  int inc = c;
  for (int off = 1; off < 64; off <<= 1) {
    int t = __shfl_up(inc, off);
    if (lane >= off) inc += t;
  }
  int excl = inc - c;
  int total = __shfl(inc, 63);
  if (lane == 0) meta[0] = total < 64 ? total : 64;
  int idx = excl;
  for (int i = 0; i < per; ++i) {
    if (cmf[base + i] > thr) {
      if (idx < 64) meta[1 + idx] = base + i;
      idx++;
    }
  }
  for (int j = total + lane; j < 64; j += 64) meta[1 + j] = -1;
}

// ---------------- row-wise int8 quant + outlier gather -------------------
// qdst int8 [rows,K]; sdst fp32 scale/row; odst bf16 [rows,64] outlier panel.
// zero_outlier=1 (x): outlier cols excluded from max and quantized to 0.
// zero_outlier=0 (W): full-row scale, all cols quantized; raw vals gathered.
__global__ __launch_bounds__(256) void k_quant8(
    const float* __restrict__ src, const u32* __restrict__ cm,
    const int* __restrict__ thr_i, const int* __restrict__ meta,
    char* __restrict__ qdst, float* __restrict__ sdst, u16* __restrict__ odst,
    int K, int zero_outlier) {
  int row = blockIdx.x;
  int tid = threadIdx.x;
  float thr = load_thr(thr_i);
  const float* sr = src + (size_t)row * K;
  const float* cmf = (const float*)cm;

  float v[16];
  u32 omask = 0;
  float lmax = 0.f;
#pragma unroll
  for (int j = 0; j < 4; ++j) {
    int c4 = j * 256 + tid;
    f32x4 val = *(const f32x4*)&sr[c4 * 4];
    f32x4 cv = *(const f32x4*)&cmf[c4 * 4];
#pragma unroll
    for (int i = 0; i < 4; ++i) {
      float xv = val[i];
      v[j * 4 + i] = xv;
      bool is_out = cv[i] > thr;
      if (is_out) omask |= 1u << (j * 4 + i);
      if (!is_out || !zero_outlier) lmax = fmaxf(lmax, fabsf(xv));
    }
  }
  float m = lmax;
#pragma unroll
  for (int off = 32; off >= 1; off >>= 1) m = fmaxf(m, __shfl_down(m, off));
  __shared__ float red[4];
  int lane = tid & 63, wv = tid >> 6;
  if (lane == 0) red[wv] = m;
  __syncthreads();
  float rm = fmaxf(fmaxf(red[0], red[1]), fmaxf(red[2], red[3]));
  float s = fmaxf(rm / 127.0f, 1e-8f);

  u32* q32 = (u32*)(qdst + (size_t)row * K);
#pragma unroll
  for (int j = 0; j < 4; ++j) {
    int c4 = j * 256 + tid;
    u32 pk = 0;
#pragma unroll
    for (int i = 0; i < 4; ++i) {
      float xv = v[j * 4 + i];
      int iq;
      if (zero_outlier && (omask & (1u << (j * 4 + i)))) {
        iq = 0;
      } else {
        float q = rintf(xv / s);  // round-half-even, matches jnp.round
        q = fminf(fmaxf(q, -127.f), 127.f);
        iq = (int)q;
      }
      pk |= ((u32)(u8)(char)iq) << (8 * i);
    }
    q32[c4] = pk;
  }
  if (tid == 0) sdst[row] = s;
  if (tid < 64) {
    int n_out = meta[0];
    int oc = meta[1 + tid];
    u16 ov = 0;
    if (tid < n_out && oc >= 0) ov = f2bf(sr[oc]);
    odst[(size_t)row * 64 + tid] = ov;
  }
}

// ---------------- int8 8-phase 256x256 GEMM + fp outlier epilogue --------
// out = sx[m]*sw[n]*(qx @ qw^T) + x_o @ w_o^T + bias
// m201 template geometry, BK=128 int8 (same 128 B/row half-tiles, same
// staging/swizzle/vmcnt ledger), i8 32x32x32 MFMA via inline asm.
__global__ __launch_bounds__(512, 2) void k_gemm_i8(
    const char* __restrict__ qx, const char* __restrict__ qw,
    const float* __restrict__ sx, const float* __restrict__ sw,
    const float* __restrict__ bias, const char* __restrict__ xo,
    const char* __restrict__ wo, float* __restrict__ out, int M, int N,
    int K) {
  extern __shared__ char lds_raw[];
  int tid = threadIdx.x;
  int lane = tid & 63, wave = tid >> 6;
  int wm = wave >> 2, wn = wave & 3;  // 2 x 4 wave grid

  // T1: bijective XCD swizzle (nwg % 8 == 0)
  int nwg = gridDim.x;
  int bid = blockIdx.x;
  int swzb = (bid & 7) * (nwg >> 3) + (bid >> 3);
  int nbn = N / 256;
  int bm = swzb / nbn, bn = swzb % nbn;
  int r0 = bm * 256, c0 = bn * 256;

  // half-tile = 128 rows x 128 B = 16 KB = 1024 granules of 16 B.
  // LDS dest linear; source granule col pre-swizzled (gc ^= row&7).
  int g0 = tid, g1 = 512 + tid;
  int row0s = g0 >> 3, col0b = ((g0 & 7) ^ (row0s & 7)) << 4;
  int row1s = g1 >> 3, col1b = ((g1 & 7) ^ (row1s & 7)) << 4;

#define AH(buf, h) (lds_raw + (buf) * 65536 + (h) * 16384)
#define BHALF(buf, h) (lds_raw + (buf) * 65536 + 32768 + (h) * 16384)

#define STAGE(dstb, srcb, rowbase, kb)                                        \
  {                                                                           \
    gload_lds16((srcb) + (size_t)((rowbase) + row0s) * K + (kb) + col0b,      \
                (dstb) + g0 * 16);                                            \
    gload_lds16((srcb) + (size_t)((rowbase) + row1s) * K + (kb) + col1b,      \
                (dstb) + g1 * 16);                                            \
  }

  // frag read: 16 int8 at row rl, k-bytes ks*32 + (lane>>5)*16, slot^row&7
#define LDAI(dst, buf, q, ks)                                                 \
  {                                                                           \
    int rl = (q) * 32 + (lane & 31);                                          \
    dst = *(const i32x4*)(AH(buf, wm) + rl * 128 +                            \
                          ((((ks) * 2 + (lane >> 5)) ^ (rl & 7)) << 4));      \
  }
#define LDBI(dst, buf, nf, ks)                                                \
  {                                                                           \
    int rl = ((wn & 1) << 6) + (nf) * 32 + (lane & 31);                       \
    dst = *(const i32x4*)(BHALF(buf, wn >> 1) + rl * 128 +                    \
                          ((((ks) * 2 + (lane >> 5)) ^ (rl & 7)) << 4));      \
  }

#define MFI(q, nf, av, bv)                                                    \
  asm volatile("v_mfma_i32_32x32x32_i8 %0, %1, %2, %0"                        \
               : "+v"(acc[q][nf])                                             \
               : "v"(av), "v"(bv))

  // one phase: M-frag quadrant q over full BK=128; 8 MFMA
#define PHASEI(buf, q, PREF, TAILWAIT)                                        \
  {                                                                           \
    if ((q) == 0) {                                                           \
      LDBI(Bfi[0], buf, 0, 0); LDBI(Bfi[1], buf, 0, 1);                       \
      LDBI(Bfi[2], buf, 0, 2); LDBI(Bfi[3], buf, 0, 3);                       \
      LDBI(Bfi[4], buf, 1, 0); LDBI(Bfi[5], buf, 1, 1);                       \
      LDBI(Bfi[6], buf, 1, 2); LDBI(Bfi[7], buf, 1, 3);                       \
    }                                                                         \
    i32x4 a0, a1, a2, a3;                                                     \
    LDAI(a0, buf, q, 0);                                                      \
    LDAI(a1, buf, q, 1);                                                      \
    LDAI(a2, buf, q, 2);                                                      \
    LDAI(a3, buf, q, 3);                                                      \
    PREF;                                                                     \
    if ((q) == 0) asm volatile("s_waitcnt lgkmcnt(8)" ::: "memory");          \
    __builtin_amdgcn_s_barrier();                                             \
    asm volatile("s_waitcnt lgkmcnt(0)" ::: "memory");                        \
    __builtin_amdgcn_s_setprio(1);                                            \
    MFI(q, 0, a0, Bfi[0]);                                                    \
    MFI(q, 0, a1, Bfi[1]);                                                    \
    MFI(q, 0, a2, Bfi[2]);                                                    \
    MFI(q, 0, a3, Bfi[3]);                                                    \
    MFI(q, 1, a0, Bfi[4]);                                                    \
    MFI(q, 1, a1, Bfi[5]);                                                    \
    MFI(q, 1, a2, Bfi[6]);                                                    \
    MFI(q, 1, a3, Bfi[7]);                                                    \
    __builtin_amdgcn_s_setprio(0);                                            \
    TAILWAIT;                                                                 \
    __builtin_amdgcn_s_barrier();                                             \
  }

#define WV4 asm volatile("s_waitcnt vmcnt(4)" ::: "memory")

  i32x16 acc[4][2] = {};
  i32x4 Bfi[8];

  // prologue: tile0 (A+B) into buf0, tile1 B into buf1
  STAGE(AH(0, 0), qx, r0, 0);
  STAGE(AH(0, 1), qx, r0 + 128, 0);
  STAGE(BHALF(0, 0), qw, c0, 0);
  STAGE(BHALF(0, 1), qw, c0 + 128, 0);
  STAGE(BHALF(1, 0), qw, c0, 128);
  STAGE(BHALF(1, 1), qw, c0 + 128, 128);
  WV4;
  __builtin_amdgcn_s_barrier();

  int nit = K / 256;  // 2 K-tiles (BK=128) per iteration
  for (int it = 0; it < nit; ++it) {
    int kt1 = it * 256 + 128;  // tile t+1 (always < K)
    int kb2 = it * 256 + 256;
    kb2 = (kb2 < K) ? kb2 : 0;  // tile t+2 (clamped; data unused if OOB)
    int kb3 = it * 256 + 384;
    kb3 = (kb3 < K) ? kb3 : 0;  // tile t+3 (clamped)
    // phases 1-4: tile t from buf0
    PHASEI(0, 0, STAGE(AH(1, 0), qx, r0, kt1), );
    PHASEI(0, 1, STAGE(AH(1, 1), qx, r0 + 128, kt1), );
    PHASEI(0, 2, STAGE(BHALF(0, 0), qw, c0, kb2), );
    PHASEI(0, 3, STAGE(BHALF(0, 1), qw, c0 + 128, kb2), WV4);
    // phases 5-8: tile t+1 from buf1
    PHASEI(1, 0, STAGE(AH(0, 0), qx, r0, kb2), );
    PHASEI(1, 1, STAGE(AH(0, 1), qx, r0 + 128, kb2), );
    PHASEI(1, 2, STAGE(BHALF(1, 0), qw, c0, kb3), );
    PHASEI(1, 3, STAGE(BHALF(1, 1), qw, c0 + 128, kb3), WV4);
  }

  // --------- epilogue: stage outlier panels (each 256 rows x 128 B) ------
  // into buf0's A/B regions (buf1's pending clamped stores don't overlap).
#pragma unroll
  for (int i = 0; i < 4; ++i) {
    int g = tid + i * 512;
    int rw = g >> 3;
    int cb = ((g & 7) ^ (rw & 7)) << 4;
    gload_lds16(xo + (size_t)(r0 + rw) * 128 + cb, lds_raw + g * 16);
  }
#pragma unroll
  for (int i = 0; i < 4; ++i) {
    int g = tid + i * 512;
    int rw = g >> 3;
    int cb = ((g & 7) ^ (rw & 7)) << 4;
    gload_lds16(wo + (size_t)(c0 + rw) * 128 + cb, lds_raw + 32768 + g * 16);
  }

  // scale conversion (hides outlier-stage latency):
  // C/D 32x32 layout: col=lane&31, row=(reg&3)+8*(reg>>2)+4*(lane>>5)
  f32x16 facc[4][2];
  float swv0 = sw[c0 + wn * 64 + (lane & 31)];
  float swv1 = sw[c0 + wn * 64 + 32 + (lane & 31)];
#pragma unroll
  for (int fm = 0; fm < 4; ++fm) {
    int gmb = r0 + wm * 128 + fm * 32 + 4 * (lane >> 5);
    f32x4 s4a = *(const f32x4*)&sx[gmb];
    f32x4 s4b = *(const f32x4*)&sx[gmb + 8];
    f32x4 s4c = *(const f32x4*)&sx[gmb + 16];
    f32x4 s4d = *(const f32x4*)&sx[gmb + 24];
#pragma unroll
    for (int reg = 0; reg < 16; ++reg) {
      float sxv = (reg < 4) ? s4a[reg & 3]
                : (reg < 8) ? s4b[reg & 3]
                : (reg < 12) ? s4c[reg & 3] : s4d[reg & 3];
      facc[fm][0][reg] = (float)acc[fm][0][reg] * sxv * swv0;
      facc[fm][1][reg] = (float)acc[fm][1][reg] * sxv * swv1;
    }
  }

  asm volatile("s_waitcnt vmcnt(0)" ::: "memory");
  __builtin_amdgcn_s_barrier();

  // outlier bf16 GEMM over K=64 into the scaled accumulators
#pragma unroll
  for (int ks = 0; ks < 4; ++ks) {
    int rn0 = wn * 64 + (lane & 31);
    int rn1 = rn0 + 32;
    bf16x8 ob0 = *(const bf16x8*)(lds_raw + 32768 + rn0 * 128 +
                                  (((ks * 2 + (lane >> 5)) ^ (rn0 & 7)) << 4));
    bf16x8 ob1 = *(const bf16x8*)(lds_raw + 32768 + rn1 * 128 +
                                  (((ks * 2 + (lane >> 5)) ^ (rn1 & 7)) << 4));
#pragma unroll
    for (int fm = 0; fm < 4; ++fm) {
      int rl = wm * 128 + fm * 32 + (lane & 31);
      bf16x8 oa = *(const bf16x8*)(lds_raw + rl * 128 +
                                   (((ks * 2 + (lane >> 5)) ^ (rl & 7)) << 4));
      facc[fm][0] = __builtin_amdgcn_mfma_f32_32x32x16_bf16(oa, ob0,
                                                            facc[fm][0], 0, 0, 0);
      facc[fm][1] = __builtin_amdgcn_mfma_f32_32x32x16_bf16(oa, ob1,
                                                            facc[fm][1], 0, 0, 0);
    }
  }

  float bv0 = bias[c0 + wn * 64 + (lane & 31)];
  float bv1 = bias[c0 + wn * 64 + 32 + (lane & 31)];
  int gc0 = c0 + wn * 64 + (lane & 31);
#pragma unroll
  for (int fm = 0; fm < 4; ++fm) {
#pragma unroll
    for (int reg = 0; reg < 16; ++reg) {
      int gm = r0 + wm * 128 + fm * 32 + (reg & 3) + 8 * (reg >> 2) +
               4 * (lane >> 5);
      float* orow = out + (size_t)gm * N + gc0;
      orow[0] = facc[fm][0][reg] + bv0;
      orow[32] = facc[fm][1][reg] + bv1;
    }
  }
}

extern "C" void kernel_launch(void* const* d_in, const int* in_sizes, int n_in,
                              void* d_out, int out_size, void* d_ws,
                              size_t ws_size, hipStream_t stream) {
  const float* x = (const float*)d_in[0];
  const float* W = (const float*)d_in[1];
  const float* bias = (const float*)d_in[2];
  const int* thr = (const int*)d_in[3];
  float* out = (float*)d_out;

  int N = in_sizes[2];
  int K = in_sizes[1] / N;
  int M = in_sizes[0] / K;

  char* ws = (char*)d_ws;
  u32* cm = (u32*)ws;                       // K u32 (16 KB)
  int* meta = (int*)(ws + 16384);           // 65 ints
  float* sx = (float*)(ws + 32768);         // M f32
  float* sw = (float*)(ws + 32768 + (size_t)M * 4);          // N f32
  char* xo = ws + 32768 + (size_t)(M + N) * 4;               // M*64 bf16
  char* wo = xo + (size_t)M * 128;                           // N*64 bf16
  char* qx = wo + (size_t)N * 128;                           // M*K int8
  char* qw = qx + (size_t)M * K;                             // N*K int8

  k_init_cm<<<dim3((K + 255) / 256), dim3(256), 0, stream>>>(cm, K);

  {
    int gx = K / 1024;
    int gy = 128;
    int rpb = (M + gy - 1) / gy;
    k_colmax<<<dim3(gx, gy), dim3(256), 0, stream>>>(x, cm, M, K, rpb);
  }

  k_ocols<<<dim3(1), dim3(64), 0, stream>>>(cm, thr, K, meta);

  k_quant8<<<dim3(M), dim3(256), 0, stream>>>(x, cm, thr, meta, qx, sx,
                                              (u16*)xo, K, 1);
  k_quant8<<<dim3(N), dim3(256), 0, stream>>>(W, cm, thr, meta, qw, sw,
                                              (u16*)wo, K, 0);

  (void)hipFuncSetAttribute((const void*)k_gemm_i8,
                            hipFuncAttributeMaxDynamicSharedMemorySize,
                            131072);
  int nwg = (M / 256) * (N / 256);
  k_gemm_i8<<<dim3(nwg), dim3(512), 131072, stream>>>(qx, qw, sx, sw, bias,
                                                      xo, wo, out, M, N, K);
}